// Round 13
// baseline (48.758 us; speedup 1.0000x reference)
//
#include <hip/hip_runtime.h>

typedef __bf16 bf16;
typedef __bf16 bf16x4 __attribute__((ext_vector_type(4)));
typedef __bf16 bf16x8 __attribute__((ext_vector_type(8)));
typedef float  f32x4  __attribute__((ext_vector_type(4)));

#define ALPHA 0.2f
#define MLP_ALPHA 0.01f
#define LN_EPS 1e-5f

constexpr int Bb = 4;
constexpr int Nn = 4096;
constexpr int Ff = 256;   // FIN == FOUT
constexpr int Kk = 64;    // chunk rows
constexpr int Cc = 64;    // N / k

__device__ __forceinline__ f32x4 MFMA(bf16x8 a, bf16x8 b, f32x4 c) {
  return __builtin_amdgcn_mfma_f32_16x16x32_bf16(a, b, c, 0, 0, 0);
}
__device__ __forceinline__ bf16x4 pack4(f32x4 v) {
  bf16x4 r; r[0]=(bf16)v[0]; r[1]=(bf16)v[1]; r[2]=(bf16)v[2]; r[3]=(bf16)v[3]; return r;
}
__device__ __forceinline__ bf16x8 cvt8(f32x4 a, f32x4 b) {
  bf16x8 v;
  #pragma unroll
  for (int d = 0; d < 4; ++d) { v[d] = (bf16)a[d]; v[4+d] = (bf16)b[d]; }
  return v;
}
// 512B-row buffers: XOR bits 4-7 (16 slots)
__device__ __forceinline__ int swz512(int i, int inrow) { return i*512 + (inrow ^ ((i & 15) << 4)); }
// 128B-row buffers: XOR bits 4-6
__device__ __forceinline__ int swz128(int f, int inrow) { return f*128 + (inrow ^ ((f & 7) << 4)); }

// ---------------- prep: weights -> bf16 frag layout ; wa = W @ a (f32) -------
// frag[mat][kt(8)][nt(16)][lane(64)][jj(8)] ; element = W[kt*32+(l>>4)*8+jj][nt*16+(l&15)]
__global__ __launch_bounds__(256) void prep_weights(
    const float* __restrict__ W0, const float* __restrict__ W1,
    const float* __restrict__ W2, const float* __restrict__ W3,
    const float* __restrict__ a_vec,
    bf16* __restrict__ outw, float* __restrict__ wa)
{
  if (blockIdx.x == 128) {                 // wa[k] = dot(W0[k,:], a) (exact f32)
    int k = threadIdx.x;
    const float* row = W0 + k * Ff;
    float s = 0.f;
    for (int j = 0; j < Ff; j += 4) {
      f32x4 wv = *(const f32x4*)(row + j);
      f32x4 av = *(const f32x4*)(a_vec + j);
      s += wv[0]*av[0] + wv[1]*av[1] + wv[2]*av[2] + wv[3]*av[3];
    }
    wa[k] = s;
    return;
  }
  int t = blockIdx.x * 256 + threadIdx.x;  // [0, 32768)
  int l = t & 63, nt = (t >> 6) & 15, kt = (t >> 10) & 7, mat = t >> 13;
  const float* src = (mat==0) ? W0 : (mat==1) ? W1 : (mat==2) ? W2 : W3;
  int n  = nt*16 + (l & 15);
  int k0 = kt*32 + (l >> 4)*8;
  bf16x8 v;
  #pragma unroll
  for (int jj = 0; jj < 8; ++jj) v[jj] = (bf16)src[(k0 + jj)*Ff + n];
  *(bf16x8*)(outw + (size_t)t * 8) = v;
}

__device__ __forceinline__ void prefetch_af(const bf16* __restrict__ wfrag, int mat,
                                            bf16x8 pf[4][2], int w, int l) {
  #pragma unroll
  for (int kt = 0; kt < 4; ++kt)
    #pragma unroll
    for (int r = 0; r < 2; ++r)
      pf[kt][r] = *(const bf16x8*)(wfrag + ((((size_t)mat*8 + kt)*16 + (w*2 + r))*64 + l)*8);
}

// MLP stage: kt 0-3 weights come from pre-barrier prefetch regs, kt 4-7 inline.
__device__ __forceinline__ void mlp_stage(const bf16* __restrict__ wfrag, int mat,
                                          const bf16* inB, f32x4 acc[4][2],
                                          bf16x8 pf[4][2], int w, int l)
{
  const int g = l >> 4, li = l & 15;
  #pragma unroll
  for (int kt = 0; kt < 8; ++kt) {
    bf16x8 af[2];
    if (kt < 4) { af[0] = pf[kt][0]; af[1] = pf[kt][1]; }
    else {
      #pragma unroll
      for (int r = 0; r < 2; ++r)
        af[r] = *(const bf16x8*)(wfrag + ((((size_t)mat*8 + kt)*16 + (w*2 + r))*64 + l)*8);
    }
    bf16x8 bfr[4];
    #pragma unroll
    for (int nt = 0; nt < 4; ++nt) {
      int i = nt*16 + li;
      bfr[nt] = *(const bf16x8*)((const char*)inB + swz512(i, (kt*32 + g*8)*2));
    }
    #pragma unroll
    for (int nt = 0; nt < 4; ++nt)
      #pragma unroll
      for (int r = 0; r < 2; ++r)
        acc[nt][r] = MFMA(af[r], bfr[nt], acc[nt][r]);
  }
}

// One block per chunk, 8 waves, 5 barriers. NO h staging: phase0 A-frags come
// straight from global (h chunk is L2-resident after the e-pass). whcT is
// wave-private => phase0->PV needs no barrier. Softmax runs pre-B1.
__global__ __launch_bounds__(512, 2) void gat_mfma(
    const float* __restrict__ h,   const float* __restrict__ adj,
    const float* __restrict__ gln, const float* __restrict__ bln,
    const float* __restrict__ b1,  const float* __restrict__ b2,
    const float* __restrict__ b3,
    const bf16* __restrict__ wfrag, const float* __restrict__ wa,
    float* __restrict__ out)
{
  __shared__ bf16 bufA[Ff * Kk];   // whcT [256 f][64 j] (swz128, wave-private panels) -> y1 (swz512)
  __shared__ bf16 bufB[Kk * Ff];   // x [64 i][256 f] -> y2 (swz512)
  __shared__ bf16 sS[Kk * Kk];     // S [64 i][64 j] (swz128)
  __shared__ float lnS[Kk * 8], lnQ[Kk * 8];

  const int t = threadIdx.x, l = t & 63, w = t >> 6, g = l >> 4, li = l & 15;
  const int bc = blockIdx.x, b = bc >> 6, c = bc & 63;
  const size_t rbase = (size_t)b * Nn + c * Kk;

  // adj prefetch: wave w rows w*8+rr, lane = j
  float adjv[8];
  #pragma unroll
  for (int rr = 0; rr < 8; ++rr)
    adjv[rr] = adj[(rbase + w*8 + rr) * Nn + (size_t)c*Kk + l];

  // ---------------- e-pass: e = leaky(h[i,:].wa) in f32 (first h touch) ------
  // same mapping as R12: thread covers row t>>3, cols (t&7)*32..+31
  float pl;
  {
    const int i  = t >> 3;
    const int k0 = (t & 7) * 32;
    const float* hp = h + (rbase + i) * Ff + k0;
    float p = 0.f;
    #pragma unroll
    for (int u = 0; u < 4; ++u) {
      f32x4 h0 = *(const f32x4*)(hp + u*8);
      f32x4 h1 = *(const f32x4*)(hp + u*8 + 4);
      f32x4 w0 = *(const f32x4*)(wa + k0 + u*8);
      f32x4 w1 = *(const f32x4*)(wa + k0 + u*8 + 4);
      p += h0[0]*w0[0] + h0[1]*w0[1] + h0[2]*w0[2] + h0[3]*w0[3]
         + h1[0]*w1[0] + h1[1]*w1[1] + h1[2]*w1[2] + h1[3]*w1[3];
    }
    p += __shfl_xor(p, 1); p += __shfl_xor(p, 2); p += __shfl_xor(p, 4);
    pl = (p >= 0.f) ? p : ALPHA * p;   // e for row w*8+(l>>3)
  }

  // hoist phase0 kt=0 A-loads (global) so they fly under softmax + B1
  f32x4 a00[4], a01[4];
  #pragma unroll
  for (int rt = 0; rt < 4; ++rt) {
    const float* ap = h + (rbase + rt*16 + li) * Ff + g*8;
    a00[rt] = *(const f32x4*)(ap);
    a01[rt] = *(const f32x4*)(ap + 4);
  }

  // ---------------- softmax (rows w*8+rr, own-wave e) -> S pre-B1 -------------
  #pragma unroll
  for (int rr = 0; rr < 8; ++rr) {
    int i = w*8 + rr;
    float e  = __shfl(pl, rr*8);
    float x  = adjv[rr] * e;
    float m = x;
    #pragma unroll
    for (int off = 32; off; off >>= 1) m = fmaxf(m, __shfl_xor(m, off));
    float pe = __expf(x - m);
    float s = pe;
    #pragma unroll
    for (int off = 32; off; off >>= 1) s += __shfl_xor(s, off);
    *(bf16*)((char*)sS + swz128(i, l*2)) = (bf16)(pe / s);
  }
  __syncthreads();   // B1: sS complete (cheap: only softmax ahead of it)

  // ---------------- phase 0: whcT = (h @ W)^T  (A from GLOBAL, L2-hot) -------
  f32x4 acc1[2][4];   // [q: f col-tile][rt: j row-tile]
  #pragma unroll
  for (int q = 0; q < 2; ++q)
    #pragma unroll
    for (int rt = 0; rt < 4; ++rt) acc1[q][rt] = (f32x4){0.f,0.f,0.f,0.f};
  #pragma unroll
  for (int kt = 0; kt < 8; ++kt) {
    bf16x8 af[4];
    if (kt == 0) {
      #pragma unroll
      for (int rt = 0; rt < 4; ++rt) af[rt] = cvt8(a00[rt], a01[rt]);
    } else {
      #pragma unroll
      for (int rt = 0; rt < 4; ++rt) {
        const float* ap = h + (rbase + rt*16 + li) * Ff + kt*32 + g*8;
        af[rt] = cvt8(*(const f32x4*)(ap), *(const f32x4*)(ap + 4));
      }
    }
    #pragma unroll
    for (int q = 0; q < 2; ++q) {
      bf16x8 bfr = *(const bf16x8*)(wfrag + (((size_t)kt*16 + (w*2 + q))*64 + l)*8);
      #pragma unroll
      for (int rt = 0; rt < 4; ++rt) acc1[q][rt] = MFMA(af[rt], bfr, acc1[q][rt]);
    }
  }
  // whcT store — wave-private panel; NO barrier before PV (same-wave LDS order)
  #pragma unroll
  for (int q = 0; q < 2; ++q) {
    int f = (w*2 + q)*16 + li;
    #pragma unroll
    for (int rt = 0; rt < 4; ++rt) {
      int j0 = rt*16 + g*4;
      *(bf16x4*)((char*)bufA + swz128(f, j0*2)) = pack4(acc1[q][rt]);
    }
  }

  // ---------------- PV: xT = whcT @ S^T -> x row-major ----------------
  f32x4 xr[4][2];    // residual, kept in regs
  #pragma unroll
  for (int nt = 0; nt < 4; ++nt)
    #pragma unroll
    for (int r = 0; r < 2; ++r) xr[nt][r] = (f32x4){0.f,0.f,0.f,0.f};
  #pragma unroll
  for (int kt = 0; kt < 2; ++kt) {
    int koff = (kt*32 + g*8)*2;
    bf16x8 af[2], bfr[4];
    #pragma unroll
    for (int r = 0; r < 2; ++r) {
      int f = (w*2 + r)*16 + li;
      af[r] = *(const bf16x8*)((const char*)bufA + swz128(f, koff));   // own panel
    }
    #pragma unroll
    for (int nt = 0; nt < 4; ++nt) {
      int i = nt*16 + li;
      bfr[nt] = *(const bf16x8*)((const char*)sS + swz128(i, koff));   // ordered by B1
    }
    #pragma unroll
    for (int nt = 0; nt < 4; ++nt)
      #pragma unroll
      for (int r = 0; r < 2; ++r)
        xr[nt][r] = MFMA(af[r], bfr[nt], xr[nt][r]);
  }
  #pragma unroll
  for (int nt = 0; nt < 4; ++nt) {
    int i = nt*16 + li;
    #pragma unroll
    for (int r = 0; r < 2; ++r) {
      int f0 = (w*2 + r)*16 + g*4;
      *(bf16x4*)((char*)bufB + swz512(i, f0*2)) = pack4(xr[nt][r]);
    }
  }

  // ---------------- MLP: 3 stages, weight prefetch across each barrier --------
  bf16x8 pf[4][2];
  f32x4 acc3[4][2];
  prefetch_af(wfrag, 1, pf, w, l);     // issued pre-barrier; drained at barrier
  __syncthreads();   // B2: x ready; whcT reads (pre-barrier, own-wave) done

  #pragma unroll
  for (int nt = 0; nt < 4; ++nt)
    #pragma unroll
    for (int r = 0; r < 2; ++r) acc3[nt][r] = (f32x4){0.f,0.f,0.f,0.f};
  mlp_stage(wfrag, 1, bufB, acc3, pf, w, l);       // y1 = leaky(x W1 + b1)
  #pragma unroll
  for (int nt = 0; nt < 4; ++nt) {
    int i = nt*16 + li;
    #pragma unroll
    for (int r = 0; r < 2; ++r) {
      f32x4 v;
      #pragma unroll
      for (int e = 0; e < 4; ++e) {
        float x = acc3[nt][r][e] + b1[(w*2 + r)*16 + g*4 + e];
        v[e] = (x >= 0.f) ? x : MLP_ALPHA * x;
      }
      int f0 = (w*2 + r)*16 + g*4;
      *(bf16x4*)((char*)bufA + swz512(i, f0*2)) = pack4(v);
    }
  }
  prefetch_af(wfrag, 2, pf, w, l);
  __syncthreads();   // B3: y1 ready; bufB x-reads done

  #pragma unroll
  for (int nt = 0; nt < 4; ++nt)
    #pragma unroll
    for (int r = 0; r < 2; ++r) acc3[nt][r] = (f32x4){0.f,0.f,0.f,0.f};
  mlp_stage(wfrag, 2, bufA, acc3, pf, w, l);       // y2 = leaky(y1 W2 + b2)
  #pragma unroll
  for (int nt = 0; nt < 4; ++nt) {
    int i = nt*16 + li;
    #pragma unroll
    for (int r = 0; r < 2; ++r) {
      f32x4 v;
      #pragma unroll
      for (int e = 0; e < 4; ++e) {
        float x = acc3[nt][r][e] + b2[(w*2 + r)*16 + g*4 + e];
        v[e] = (x >= 0.f) ? x : MLP_ALPHA * x;
      }
      int f0 = (w*2 + r)*16 + g*4;
      *(bf16x4*)((char*)bufB + swz512(i, f0*2)) = pack4(v);
    }
  }
  prefetch_af(wfrag, 3, pf, w, l);
  __syncthreads();   // B4: y2 ready; bufA y1-reads done

  #pragma unroll
  for (int nt = 0; nt < 4; ++nt)
    #pragma unroll
    for (int r = 0; r < 2; ++r) acc3[nt][r] = (f32x4){0.f,0.f,0.f,0.f};
  mlp_stage(wfrag, 3, bufB, acc3, pf, w, l);       // y3 = y2 W3 (+b3 in epilogue)

  // ---------------- epilogue: +b3 +x ; LayerNorm over f ; store ----------------
  {
    float bv[2][4], gv[2][4], btv[2][4];
    #pragma unroll
    for (int r = 0; r < 2; ++r)
      #pragma unroll
      for (int e = 0; e < 4; ++e) {
        int f = (w*2 + r)*16 + g*4 + e;
        bv[r][e] = b3[f]; gv[r][e] = gln[f]; btv[r][e] = bln[f];
      }
    #pragma unroll
    for (int nt = 0; nt < 4; ++nt) {
      float s = 0.f, qq = 0.f;
      #pragma unroll
      for (int r = 0; r < 2; ++r)
        #pragma unroll
        for (int e = 0; e < 4; ++e) {
          float z = acc3[nt][r][e] + bv[r][e] + xr[nt][r][e];
          acc3[nt][r][e] = z;
          s += z; qq += z*z;
        }
      s  += __shfl_xor(s, 16);  s  += __shfl_xor(s, 32);
      qq += __shfl_xor(qq, 16); qq += __shfl_xor(qq, 32);
      if (g == 0) {
        int i = nt*16 + li;
        lnS[i*8 + w] = s;
        lnQ[i*8 + w] = qq;
      }
    }
    __syncthreads();   // B5: LN partials
    #pragma unroll
    for (int nt = 0; nt < 4; ++nt) {
      int i = nt*16 + li;
      f32x4 s0 = *(const f32x4*)&lnS[i*8];
      f32x4 s1 = *(const f32x4*)&lnS[i*8 + 4];
      f32x4 q0 = *(const f32x4*)&lnQ[i*8];
      f32x4 q1 = *(const f32x4*)&lnQ[i*8 + 4];
      float s  = s0[0]+s0[1]+s0[2]+s0[3]+s1[0]+s1[1]+s1[2]+s1[3];
      float qq = q0[0]+q0[1]+q0[2]+q0[3]+q1[0]+q1[1]+q1[2]+q1[3];
      float mu  = s * (1.f/256.f);
      float var = qq * (1.f/256.f) - mu*mu;
      float rs  = rsqrtf(var + LN_EPS);
      #pragma unroll
      for (int r = 0; r < 2; ++r) {
        float4 o;
        o.x = (acc3[nt][r][0] - mu)*rs*gv[r][0] + btv[r][0];
        o.y = (acc3[nt][r][1] - mu)*rs*gv[r][1] + btv[r][1];
        o.z = (acc3[nt][r][2] - mu)*rs*gv[r][2] + btv[r][2];
        o.w = (acc3[nt][r][3] - mu)*rs*gv[r][3] + btv[r][3];
        *(float4*)&out[(rbase + i)*Ff + (w*2 + r)*16 + g*4] = o;
      }
    }
  }
}

extern "C" void kernel_launch(void* const* d_in, const int* in_sizes, int n_in,
                              void* d_out, int out_size, void* d_ws, size_t ws_size,
                              hipStream_t stream) {
  (void)in_sizes; (void)n_in; (void)out_size; (void)ws_size;
  bf16*  wfrag = (bf16*)d_ws;                       // 512 KB
  float* wa    = (float*)((char*)d_ws + 512*1024);  // 1 KB
  prep_weights<<<dim3(129), dim3(256), 0, stream>>>(
      (const float*)d_in[2], (const float*)d_in[6],
      (const float*)d_in[8], (const float*)d_in[10],
      (const float*)d_in[3], wfrag, wa);
  gat_mfma<<<dim3(Bb * Cc), dim3(512), 0, stream>>>(
      (const float*)d_in[0],  (const float*)d_in[1],
      (const float*)d_in[4],  (const float*)d_in[5],
      (const float*)d_in[7],  (const float*)d_in[9],  (const float*)d_in[11],
      wfrag, wa, (float*)d_out);
}

// Round 14
// 36.041 us; speedup vs baseline: 1.3529x; 1.3529x over previous
//
#include <hip/hip_runtime.h>

typedef __bf16 bf16;
typedef __bf16 bf16x4 __attribute__((ext_vector_type(4)));
typedef __bf16 bf16x8 __attribute__((ext_vector_type(8)));
typedef float  f32x4  __attribute__((ext_vector_type(4)));

#define ALPHA 0.2f
#define MLP_ALPHA 0.01f
#define LN_EPS 1e-5f

constexpr int Bb = 4;
constexpr int Nn = 4096;
constexpr int Ff = 256;   // FIN == FOUT
constexpr int Kk = 64;    // chunk rows
constexpr int Cc = 64;    // N / k

__device__ __forceinline__ f32x4 MFMA(bf16x8 a, bf16x8 b, f32x4 c) {
  return __builtin_amdgcn_mfma_f32_16x16x32_bf16(a, b, c, 0, 0, 0);
}
__device__ __forceinline__ bf16x4 pack4(f32x4 v) {
  bf16x4 r; r[0]=(bf16)v[0]; r[1]=(bf16)v[1]; r[2]=(bf16)v[2]; r[3]=(bf16)v[3]; return r;
}
// 512B-row buffers: XOR bits 4-7 (16 slots)
__device__ __forceinline__ int swz512(int i, int inrow) { return i*512 + (inrow ^ ((i & 15) << 4)); }
// 128B-row buffers: XOR bits 4-6
__device__ __forceinline__ int swz128(int f, int inrow) { return f*128 + (inrow ^ ((f & 7) << 4)); }

// ---------------- prep: weights -> bf16 frag layout ; wa = W @ a (f32) -------
// frag[mat][kt(8)][nt(16)][lane(64)][jj(8)] ; element = W[kt*32+(l>>4)*8+jj][nt*16+(l&15)]
__global__ __launch_bounds__(256) void prep_weights(
    const float* __restrict__ W0, const float* __restrict__ W1,
    const float* __restrict__ W2, const float* __restrict__ W3,
    const float* __restrict__ a_vec,
    bf16* __restrict__ outw, float* __restrict__ wa)
{
  if (blockIdx.x == 128) {                 // wa[k] = dot(W0[k,:], a) (exact f32)
    int k = threadIdx.x;
    const float* row = W0 + k * Ff;
    float s = 0.f;
    for (int j = 0; j < Ff; j += 4) {
      f32x4 wv = *(const f32x4*)(row + j);
      f32x4 av = *(const f32x4*)(a_vec + j);
      s += wv[0]*av[0] + wv[1]*av[1] + wv[2]*av[2] + wv[3]*av[3];
    }
    wa[k] = s;
    return;
  }
  int t = blockIdx.x * 256 + threadIdx.x;  // [0, 32768)
  int l = t & 63, nt = (t >> 6) & 15, kt = (t >> 10) & 7, mat = t >> 13;
  const float* src = (mat==0) ? W0 : (mat==1) ? W1 : (mat==2) ? W2 : W3;
  int n  = nt*16 + (l & 15);
  int k0 = kt*32 + (l >> 4)*8;
  bf16x8 v;
  #pragma unroll
  for (int jj = 0; jj < 8; ++jj) v[jj] = (bf16)src[(k0 + jj)*Ff + n];
  *(bf16x8*)(outw + (size_t)t * 8) = v;
}

// One block per chunk (R3/R7-proven barrier structure), 16 waves.
// S stored hi/lo (~fp24 effective) — PV chains 2 MFMAs per fragment.
__global__ __launch_bounds__(1024, 4) void gat_mfma(
    const float* __restrict__ h,   const float* __restrict__ adj,
    const float* __restrict__ gln, const float* __restrict__ bln,
    const float* __restrict__ b1,  const float* __restrict__ b2,
    const float* __restrict__ b3,
    const bf16* __restrict__ wfrag, const float* __restrict__ wa,
    float* __restrict__ out)
{
  __shared__ bf16 hbs[Kk * Ff];    // h chunk, bf16, swizzled 512B rows
  __shared__ bf16 bufA[Ff * Kk];   // whcT [256 f][64 j] (128B rows) -> y1 [64 i][256 f]
  __shared__ bf16 bufB[Kk * Ff];   // x    [64 i][256 f] -> y2
  __shared__ bf16 sShi[Kk * Kk];   // S hi [64 i][64 j], swizzled 128B rows
  __shared__ bf16 sSlo[Kk * Kk];   // S lo
  __shared__ float evec[Kk];       // e[i] (pre-leaky'd)
  __shared__ float lnS[Kk * 8], lnQ[Kk * 8];

  const int t = threadIdx.x, l = t & 63, w = t >> 6, g = l >> 4, li = l & 15;
  const int wf = w & 7;            // f-group (2 f-tiles each)
  const int wi = w >> 3;           // i/j-group (2 tiles each)
  const int bc = blockIdx.x, b = bc >> 6, c = bc & 63;
  const size_t rbase = (size_t)b * Nn + c * Kk;

  // adj prefetch: wave w rows w*4+rr, lane = j
  float adjv[4];
  #pragma unroll
  for (int rr = 0; rr < 4; ++rr)
    adjv[rr] = adj[(rbase + w*4 + rr) * Nn + (size_t)c*Kk + l];

  // ---------------- stage h -> LDS bf16 ; e[i] = leaky(h[i,:].wa) in f32 ------
  {
    const int i  = t >> 4;          // 0..63 (16 threads per row)
    const int k0 = (t & 15) * 16;
    const float* hp = h + (rbase + i) * Ff + k0;
    float p = 0.f;
    #pragma unroll
    for (int u = 0; u < 2; ++u) {
      f32x4 h0 = *(const f32x4*)(hp + u*8);
      f32x4 h1 = *(const f32x4*)(hp + u*8 + 4);
      f32x4 w0 = *(const f32x4*)(wa + k0 + u*8);
      f32x4 w1 = *(const f32x4*)(wa + k0 + u*8 + 4);
      p += h0[0]*w0[0] + h0[1]*w0[1] + h0[2]*w0[2] + h0[3]*w0[3]
         + h1[0]*w1[0] + h1[1]*w1[1] + h1[2]*w1[2] + h1[3]*w1[3];
      bf16x8 v;
      #pragma unroll
      for (int d = 0; d < 4; ++d) { v[d] = (bf16)h0[d]; v[4+d] = (bf16)h1[d]; }
      *(bf16x8*)((char*)hbs + swz512(i, (k0 + u*8)*2)) = v;
    }
    p += __shfl_xor(p, 1); p += __shfl_xor(p, 2);
    p += __shfl_xor(p, 4); p += __shfl_xor(p, 8);
    if ((t & 15) == 0) evec[i] = (p >= 0.f) ? p : ALPHA * p;
  }
  __syncthreads();   // B1: hbs + evec

  // ---------------- softmax (rows w*4+rr) -> S hi/lo bf16 swizzled ------------
  #pragma unroll
  for (int rr = 0; rr < 4; ++rr) {
    int i = w*4 + rr;
    float x = adjv[rr] * evec[i];
    float m = x;
    #pragma unroll
    for (int off = 32; off; off >>= 1) m = fmaxf(m, __shfl_xor(m, off));
    float pe = __expf(x - m);
    float s = pe;
    #pragma unroll
    for (int off = 32; off; off >>= 1) s += __shfl_xor(s, off);
    float sv = pe / s;
    bf16 hi = (bf16)sv;
    *(bf16*)((char*)sShi + swz128(i, l*2)) = hi;
    *(bf16*)((char*)sSlo + swz128(i, l*2)) = (bf16)(sv - (float)hi);
  }

  // ---------------- phase 0: whcT = (h @ W)^T  (A from LDS) ----------------
  // wave covers f-tiles (wf*2+q), j-tiles (wi*2+rt)
  f32x4 acc1[2][2];   // [q][rt]
  #pragma unroll
  for (int q = 0; q < 2; ++q)
    #pragma unroll
    for (int rt = 0; rt < 2; ++rt) acc1[q][rt] = (f32x4){0.f,0.f,0.f,0.f};
  #pragma unroll
  for (int kt = 0; kt < 8; ++kt) {
    bf16x8 af[2];
    #pragma unroll
    for (int rt = 0; rt < 2; ++rt) {
      int i = (wi*2 + rt)*16 + li;
      af[rt] = *(const bf16x8*)((const char*)hbs + swz512(i, (kt*32 + g*8)*2));
    }
    #pragma unroll
    for (int q = 0; q < 2; ++q) {
      bf16x8 bfr = *(const bf16x8*)(wfrag + (((size_t)kt*16 + (wf*2 + q))*64 + l)*8);
      #pragma unroll
      for (int rt = 0; rt < 2; ++rt) acc1[q][rt] = MFMA(af[rt], bfr, acc1[q][rt]);
    }
  }
  #pragma unroll
  for (int q = 0; q < 2; ++q) {
    int f = (wf*2 + q)*16 + li;
    #pragma unroll
    for (int rt = 0; rt < 2; ++rt) {
      int j0 = (wi*2 + rt)*16 + g*4;
      *(bf16x4*)((char*)bufA + swz128(f, j0*2)) = pack4(acc1[q][rt]);
    }
  }
  __syncthreads();   // B2: whcT + sS complete

  // ---------------- phase 2: xT = whcT @ S^T -> x row-major ----------------
  // wave covers f-tiles (wf*2+r), i-tiles (wi*2+nt)
  f32x4 xr[2][2];    // [nt][r] — residual, kept in regs
  #pragma unroll
  for (int nt = 0; nt < 2; ++nt)
    #pragma unroll
    for (int r = 0; r < 2; ++r) xr[nt][r] = (f32x4){0.f,0.f,0.f,0.f};
  #pragma unroll
  for (int kt = 0; kt < 2; ++kt) {
    int koff = (kt*32 + g*8)*2;
    bf16x8 af[2], bfrH[2], bfrL[2];
    #pragma unroll
    for (int r = 0; r < 2; ++r) {
      int f = (wf*2 + r)*16 + li;
      af[r] = *(const bf16x8*)((const char*)bufA + swz128(f, koff));
    }
    #pragma unroll
    for (int nt = 0; nt < 2; ++nt) {
      int i = (wi*2 + nt)*16 + li;
      bfrH[nt] = *(const bf16x8*)((const char*)sShi + swz128(i, koff));
      bfrL[nt] = *(const bf16x8*)((const char*)sSlo + swz128(i, koff));
    }
    #pragma unroll
    for (int nt = 0; nt < 2; ++nt)
      #pragma unroll
      for (int r = 0; r < 2; ++r) {
        xr[nt][r] = MFMA(af[r], bfrL[nt], xr[nt][r]);
        xr[nt][r] = MFMA(af[r], bfrH[nt], xr[nt][r]);
      }
  }
  #pragma unroll
  for (int nt = 0; nt < 2; ++nt) {
    int i = (wi*2 + nt)*16 + li;
    #pragma unroll
    for (int r = 0; r < 2; ++r) {
      int f0 = (wf*2 + r)*16 + g*4;
      *(bf16x4*)((char*)bufB + swz512(i, f0*2)) = pack4(xr[nt][r]);
    }
  }
  __syncthreads();   // B3: x complete

  // ---------------- MLP (transposed) ----------------
  f32x4 acc3[2][2];
  #pragma unroll
  for (int stage = 0; stage < 3; ++stage) {
    const bf16* inB = (stage == 1) ? bufA : bufB;   // x -> y1 -> y2
    #pragma unroll
    for (int nt = 0; nt < 2; ++nt)
      #pragma unroll
      for (int r = 0; r < 2; ++r) acc3[nt][r] = (f32x4){0.f,0.f,0.f,0.f};
    #pragma unroll
    for (int kt = 0; kt < 8; ++kt) {
      bf16x8 af[2], bfr[2];
      #pragma unroll
      for (int r = 0; r < 2; ++r)
        af[r] = *(const bf16x8*)(wfrag + ((((size_t)(stage+1)*8 + kt)*16 + (wf*2 + r))*64 + l)*8);
      #pragma unroll
      for (int nt = 0; nt < 2; ++nt) {
        int i = (wi*2 + nt)*16 + li;
        bfr[nt] = *(const bf16x8*)((const char*)inB + swz512(i, (kt*32 + g*8)*2));
      }
      #pragma unroll
      for (int nt = 0; nt < 2; ++nt)
        #pragma unroll
        for (int r = 0; r < 2; ++r)
          acc3[nt][r] = MFMA(af[r], bfr[nt], acc3[nt][r]);
    }
    if (stage == 2) break;
    // bias + leaky(0.01) -> staging buffer
    __syncthreads();   // input buffer fully read by all waves before overwrite
    const float* bias = (stage == 0) ? b1 : b2;
    bf16* outB = (stage == 0) ? bufA : bufB;
    #pragma unroll
    for (int nt = 0; nt < 2; ++nt) {
      int i = (wi*2 + nt)*16 + li;
      #pragma unroll
      for (int r = 0; r < 2; ++r) {
        f32x4 v;
        #pragma unroll
        for (int e = 0; e < 4; ++e) {
          float x = acc3[nt][r][e] + bias[(wf*2 + r)*16 + g*4 + e];
          v[e] = (x >= 0.f) ? x : MLP_ALPHA * x;
        }
        int f0 = (wf*2 + r)*16 + g*4;
        *(bf16x4*)((char*)outB + swz512(i, f0*2)) = pack4(v);
      }
    }
    __syncthreads();   // staged output ready
  }

  // ---------------- epilogue: +b3 +x ; LayerNorm over f ; store ----------------
  {
    float bv[2][4], gv[2][4], btv[2][4];
    #pragma unroll
    for (int r = 0; r < 2; ++r)
      #pragma unroll
      for (int e = 0; e < 4; ++e) {
        int f = (wf*2 + r)*16 + g*4 + e;
        bv[r][e] = b3[f]; gv[r][e] = gln[f]; btv[r][e] = bln[f];
      }
    #pragma unroll
    for (int nt = 0; nt < 2; ++nt) {
      float s = 0.f, qq = 0.f;
      #pragma unroll
      for (int r = 0; r < 2; ++r)
        #pragma unroll
        for (int e = 0; e < 4; ++e) {
          float z = acc3[nt][r][e] + bv[r][e] + xr[nt][r][e];
          acc3[nt][r][e] = z;
          s += z; qq += z*z;
        }
      s  += __shfl_xor(s, 16);  s  += __shfl_xor(s, 32);   // reduce over g
      qq += __shfl_xor(qq, 16); qq += __shfl_xor(qq, 32);
      if (g == 0) {
        int i = (wi*2 + nt)*16 + li;
        lnS[i*8 + wf] = s;
        lnQ[i*8 + wf] = qq;
      }
    }
    __syncthreads();   // B: LN partials
    #pragma unroll
    for (int nt = 0; nt < 2; ++nt) {
      int i = (wi*2 + nt)*16 + li;
      f32x4 s0 = *(const f32x4*)&lnS[i*8];
      f32x4 s1 = *(const f32x4*)&lnS[i*8 + 4];
      f32x4 q0 = *(const f32x4*)&lnQ[i*8];
      f32x4 q1 = *(const f32x4*)&lnQ[i*8 + 4];
      float s  = s0[0]+s0[1]+s0[2]+s0[3]+s1[0]+s1[1]+s1[2]+s1[3];
      float qq = q0[0]+q0[1]+q0[2]+q0[3]+q1[0]+q1[1]+q1[2]+q1[3];
      float mu  = s * (1.f/256.f);
      float var = qq * (1.f/256.f) - mu*mu;
      float rs  = rsqrtf(var + LN_EPS);
      #pragma unroll
      for (int r = 0; r < 2; ++r) {
        float4 o;
        o.x = (acc3[nt][r][0] - mu)*rs*gv[r][0] + btv[r][0];
        o.y = (acc3[nt][r][1] - mu)*rs*gv[r][1] + btv[r][1];
        o.z = (acc3[nt][r][2] - mu)*rs*gv[r][2] + btv[r][2];
        o.w = (acc3[nt][r][3] - mu)*rs*gv[r][3] + btv[r][3];
        *(float4*)&out[(rbase + i)*Ff + (wf*2 + r)*16 + g*4] = o;
      }
    }
  }
}

extern "C" void kernel_launch(void* const* d_in, const int* in_sizes, int n_in,
                              void* d_out, int out_size, void* d_ws, size_t ws_size,
                              hipStream_t stream) {
  (void)in_sizes; (void)n_in; (void)d_ws; (void)ws_size; (void)out_size;
  bf16*  wfrag = (bf16*)d_ws;                       // 512 KB
  float* wa    = (float*)((char*)d_ws + 512*1024);  // 1 KB
  prep_weights<<<dim3(129), dim3(256), 0, stream>>>(
      (const float*)d_in[2], (const float*)d_in[6],
      (const float*)d_in[8], (const float*)d_in[10],
      (const float*)d_in[3], wfrag, wa);
  gat_mfma<<<dim3(Bb * Cc), dim3(1024), 0, stream>>>(
      (const float*)d_in[0],  (const float*)d_in[1],
      (const float*)d_in[4],  (const float*)d_in[5],
      (const float*)d_in[7],  (const float*)d_in[9],  (const float*)d_in[11],
      wfrag, wa, (float*)d_out);
}